// Round 18
// baseline (25.878 us; speedup 1.0000x reference)
//
#include <hip/hip_runtime.h>

#define C 256
#define HW 81
#define PITCH 292   // ushorts per pixel row: [4 pad][256 ch][32 pad] (even dword pitch)
#define PITCHD 146  // dwords per pixel row; 146%32=18 -> gather tap bases ~4-apart
#define ZROW 81     // zeroed row index for invalid gather taps

typedef __fp16 h2 __attribute__((ext_vector_type(2)));  // matches builtin V2h

__device__ __forceinline__ float us2f(unsigned short u) {  // f16 bits -> f32
  union { unsigned short s; __fp16 h; } c; c.s = u; return (float)c.h;
}
__device__ __forceinline__ unsigned int pkh2(float a, float b) {  // 1x cvt_pkrtz
  union { h2 h; unsigned int i; } c;
  c.h = __builtin_amdgcn_cvt_pkrtz(a, b);
  return c.i;
}
__device__ __forceinline__ h2 as_h2(unsigned int d) {
  union { unsigned int i; h2 h; } c; c.i = d; return c.h;
}
__device__ __forceinline__ unsigned int as_u32(h2 h) {
  union { h2 h; unsigned int i; } c; c.h = h; return c.i;
}
__device__ __forceinline__ float dot2(unsigned int a, unsigned int b, float c) {
#if __has_builtin(__builtin_amdgcn_fdot2)
  return __builtin_amdgcn_fdot2(as_h2(a), as_h2(b), c, false);
#else
  h2 x = as_h2(a), y = as_h2(b);
  return fmaf((float)x.y, (float)y.y, fmaf((float)x.x, (float)y.x, c));
#endif
}
__device__ __forceinline__ float exp2_fast(float x) {
#if __has_builtin(__builtin_amdgcn_exp2f)
  return __builtin_amdgcn_exp2f(x);
#else
  return __expf(x * 0.6931471805599453f);
#endif
}

// ---------------------------------------------------------------------------
// Fully fused SeMCA. Block = (b, s): s=0 -> output rows 3..5 (+epilogue rows
// 3..5 cols 0..2 on slot 3), s=1 -> rows 6..8 AND rows 0..2 (epilogue rows
// 0..2 + zero rows 6..8 cols 0..2 all on slot 3). 1024 threads. 2 barriers.
// R18 = R17 with the PV base-pointer FIX: the PV window for channel ch
// starts at u16 index ch WITHIN THE ROW (first 4 taps hit the left pad), so
// the dword base is (ch>>1) for BOTH parities (vT for even ch, vT2 -- the
// 1-u16-left-shifted copy -- for odd ch). R17 erroneously used (ch+4)>>1 /
// (ch+3)>>1, reading the window shifted by 4 channels (absmax 0.487).
// R17's cuts under test: PV as 5x fdot2 via vT/vT2; w2 tail in w2p;
// s=1 epilogue consolidated on slot 3.
// ---------------------------------------------------------------------------
__global__ __launch_bounds__(1024) void semca_fused(
    const float* __restrict__ x, const float* __restrict__ wk,
    const float* __restrict__ bk, const float* __restrict__ w1,
    const float* __restrict__ gamma, const float* __restrict__ beta,
    const float* __restrict__ mean, const float* __restrict__ var,
    const float* __restrict__ w2, const float* __restrict__ b2,
    const float* __restrict__ wv, const float* __restrict__ bv,
    float* __restrict__ out) {
  __shared__ unsigned short xT[82 * PITCH];   // 47,888 B (row 81 = zeros), f16
  __shared__ unsigned short k1T[82 * PITCH];  // 47,888 B (row 81 = zeros), f16
  __shared__ unsigned short vT[18 * PITCH];   // 10,512 B, f16
  __shared__ unsigned short vT2[18 * PITCH];  // 10,512 B, vT shifted by 1 u16
  __shared__ unsigned short pixtab[228];      //    456 B (premultiplied by PITCH)
  __shared__ float bnf1[225];                 //    900 B (BN shift only)
  __shared__ unsigned int w1p[225 * 12];      // 10,800 B half2 pairs, BN-scaled
  __shared__ unsigned int w2p[225 * 5];       //  4,500 B half2 o-pairs + tail
  __shared__ uint2 wkp[81 * 3];               //  1,944 B wk half2 (~135 KiB tot)

  const int blk = blockIdx.x;
  const int b = (blk & 7) * 16 + ((blk >> 3) & 15);  // XCD-paired, bijective
  const int s = blk >> 7;
  const int tid = threadIdx.x;
  const float* xb = x + (size_t)b * (C * HW);

  unsigned int* xTd = (unsigned int*)xT;
  unsigned int* k1Td = (unsigned int*)k1T;
  unsigned int* vTd = (unsigned int*)vT;
  unsigned int* wkpd = (unsigned int*)wkp;

  // ---- phase 0a: issue ALL x loads first (registers), incremental walk
  float xe[11], xo[11];
  int adr[11];
  {
    int chp = tid / HW;            // single division
    int p = tid - chp * HW;
#pragma unroll
    for (int rep = 0; rep < 10; ++rep) {
      const float* base = xb + (2 * chp) * HW + p;
      xe[rep] = base[0];
      xo[rep] = base[HW];
      adr[rep] = PITCHD * p + 2 + chp;
      chp += 12;                   // advance f by 1024 = 12*81 + 52
      p += 52;
      if (p >= HW) { p -= HW; chp += 1; }
    }
    if (tid < 128) {               // tail item f = 10240 + tid
      int f = 10240 + tid;
      int c2 = f / HW, p2 = f - c2 * HW;
      xe[10] = xb[2 * c2 * HW + p2];
      xo[10] = xb[(2 * c2 + 1) * HW + p2];
      adr[10] = PITCHD * p2 + 2 + c2;
    }
  }

  // ---- phase 0b: independent work under the load shadow
  for (int t = tid; t < 810; t += 1024) {  // x channel-pad zeros
    int p = t / 10, k2 = t - (t / 10) * 10;
    xT[p * PITCH + ((k2 < 4) ? k2 : (256 + k2))] = 0;
  }
  if (tid < PITCHD) {                      // zero row 81 of xT and k1T
    xTd[PITCHD * ZROW + tid] = 0;
    k1Td[PITCHD * ZROW + tid] = 0;
  }
  for (int t = tid; t < 225; t += 1024) {  // pixtab (premul) + BN shift
    int g = t / 9, tap = t - (t / 9) * 9;
    int kh = tap / 3, kw = tap - kh * 3;
    int h = kh * 5 + g / 5, w = kw * 5 + (g - (g / 5) * 5);
    pixtab[t] = (h < 9 && w < 9) ? (unsigned short)((h * 9 + w) * PITCH)
                                 : (unsigned short)(ZROW * PITCH);
    float inv = gamma[t] * rsqrtf(var[t] + 1e-5f);
    bnf1[t] = beta[t] - mean[t] * inv;
  }
  for (int t = tid; t < 2025; t += 1024) {  // w1 packed pairs, BN-scaled
    int m = t / 9, q = t - m * 9;
    float inv = gamma[m] * rsqrtf(var[m] + 1e-5f);
    w1p[m * 12 + q] = pkh2(w1[m * 18 + q] * inv, w1[m * 18 + 9 + q] * inv);
  }
  for (int t = tid; t < 1125; t += 1024) {  // w2 packed o-pairs + tail pair
    int m = t / 5, j = t - (t / 5) * 5;
    w2p[t] = (j < 4) ? pkh2(w2[m * 9 + 2 * j], w2[m * 9 + 2 * j + 1])
                     : pkh2(w2[m * 9 + 8], 0.f);
  }
  if (tid < 486) {                          // wk packed pairs + tails
    int m = tid / 6, j = tid - (tid / 6) * 6;
    const float* wr = wk + m * 9;
    unsigned int v;
    if (j < 4)       v = pkh2(wr[2 * j], wr[2 * j + 1]);
    else if (j == 4) v = pkh2(wr[8], 0.f);
    else             v = pkh2(0.f, wr[8]);
    wkpd[m * 6 + j] = v;
  }

  // hoisted phase-1b weights: chv fixed per thread -> packed h2 registers
  const int chv = tid & 127;
  unsigned int wvp[9];
#pragma unroll
  for (int t = 0; t < 9; ++t)
    wvp[t] = pkh2(wv[(2 * chv) * 9 + t], wv[(2 * chv + 1) * 9 + t]);
  const unsigned int bvp = pkh2(bv[2 * chv], bv[2 * chv + 1]);

  // ---- phase 0c: pack (f16) + LDS write (single drain of the x loads)
#pragma unroll
  for (int rep = 0; rep < 10; ++rep) xTd[adr[rep]] = pkh2(xe[rep], xo[rep]);
  if (tid < 128) xTd[adr[10]] = pkh2(xe[10], xo[10]);

  __syncthreads();

  // ---- phase 1a: k1[p][ch] = sum_j x[p][ch+j-4]*wk[p][j] + bk[p]
  // width-8 + symmetric row-cut: 54 rows x 32 octets = 1728 calls per half.
  {
    auto k1fn8 = [&](int p, int oct) {
      const uint2* wrow2 = (const uint2*)(xTd + PITCHD * p + 4 * oct);
      uint2 r0 = wrow2[0], r1 = wrow2[1], r2 = wrow2[2], r3 = wrow2[3];
      unsigned int W[8] = {r0.x, r0.y, r1.x, r1.y, r2.x, r2.y, r3.x, r3.y};
      unsigned int A[7];
#pragma unroll
      for (int k2 = 0; k2 < 7; ++k2)
        A[k2] = (W[k2] >> 16) | (W[k2 + 1] << 16);
      const uint2* wkq = wkp + p * 3;
      uint2 wa = wkq[0], wb = wkq[1], wc = wkq[2];
      // wa.x=(w0,w1) wa.y=(w2,w3) wb.x=(w4,w5) wb.y=(w6,w7)
      // wc.x=(w8,0)  wc.y=(0,w8)
      float bkp = bk[p];
      float cc[8];
#pragma unroll
      for (int j2 = 0; j2 < 4; ++j2) {  // even ch j=2*j2, odd ch j=2*j2+1
        cc[2 * j2] =
            dot2(W[j2], wa.x, dot2(W[j2 + 1], wa.y, dot2(W[j2 + 2], wb.x,
            dot2(W[j2 + 3], wb.y, dot2(W[j2 + 4], wc.x, bkp)))));
        cc[2 * j2 + 1] =
            dot2(A[j2], wa.x, dot2(A[j2 + 1], wa.y, dot2(A[j2 + 2], wb.x,
            dot2(A[j2 + 3], wb.y, dot2(W[j2 + 4], wc.y, bkp)))));
      }
      unsigned int* dst = k1Td + PITCHD * p + 2 + 4 * oct;
      *(uint2*)dst = make_uint2(pkh2(cc[0], cc[1]), pkh2(cc[2], cc[3]));
      *(uint2*)(dst + 2) = make_uint2(pkh2(cc[4], cc[5]), pkh2(cc[6], cc[7]));
    };
    // s=0 rows {1,2,3,6,7,8}; s=1 rows {0,1,3,4,5,6} (uniform branch)
    auto prow = [&](int f) {
      int idx = f >> 5;
      int ri = idx / 9, col = idx - ri * 9;
      int row = s == 0 ? (ri + ((ri < 3) ? 1 : 3)) : (ri + ((ri >= 2) ? 1 : 0));
      return row * 9 + col;
    };
    k1fn8(prow(tid), tid & 31);
    if (tid < 704) {
      int f = 1024 + tid;
      k1fn8(prow(f), f & 31);
    }
  }

  // ---- phase 1b: v (3x3 depthwise), packed-f16 (pk_fma); writes vT + vT2
  {
    auto vfn = [&](int f) {
      int e = __builtin_amdgcn_readfirstlane(f >> 7);  // 0..17 uniform
      int r0 = e / 6;
      int i = s * 3 + r0;  // v-pixel row 0..5
      int j = e - r0 * 6;  // v-pixel col 0..5
      h2 acc = as_h2(bvp);
#pragma unroll
      for (int di = 0; di < 3; ++di) {
        int ii = i + di - 1;
        if (ii < 0) continue;  // ii <= 6 < 9 always
#pragma unroll
        for (int dj = 0; dj < 3; ++dj) {
          int jj = j + dj - 1;
          if (jj < 0) continue;  // jj <= 6 < 9 always
          unsigned int d = xTd[PITCHD * (ii * 9 + jj) + 2 + chv];
          int t = di * 3 + dj;
          acc = as_h2(d) * as_h2(wvp[t]) + acc;  // v_pk_fma_f16
        }
      }
      unsigned int u = as_u32(acc);
      vTd[PITCHD * e + 2 + chv] = u;
      vT2[PITCH * e + 3 + 2 * chv] = (unsigned short)(u & 0xffffu);
      vT2[PITCH * e + 4 + 2 * chv] = (unsigned short)(u >> 16);
    };
#pragma unroll
    for (int rep = 0; rep < 2; ++rep) vfn(tid + rep * 1024);
    if (tid < 256) vfn(2048 + tid);
  }
  if (tid < 432) {  // vT + vT2 pad zeros (12 u16 per row each)
    if (tid < 216) {
      int e = tid / 12, k2 = tid - (tid / 12) * 12;
      vT[e * PITCH + ((k2 < 4) ? k2 : (256 + k2))] = 0;  // 0..3, 260..267
    } else {
      int t2 = tid - 216;
      int e = t2 / 12, k2 = t2 - (t2 / 12) * 12;
      vT2[e * PITCH + ((k2 < 3) ? k2 : (256 + k2))] = 0; // 0..2, 259..267
    }
  }
  __syncthreads();

  // ---- phase 2: 15 instances as 4/4/4/3 (slot 3 skips k=3; no dummy)
  const int s4 = tid >> 8;  // slot 0..3 (wave-uniform)
  const int ch = tid & 255;
  const int ci0 = ch / 9;
  const int tap0 = ch - ci0 * 9;
  float* outb = out + ((size_t)b * C + ch) * HW;

  // PV base: window starts at u16 index ch within the row -> dword ch>>1.
  // Even ch: vT (pairs aligned). Odd ch: vT2 (1-u16-left-shifted copy).
  const unsigned int* pvrow =
      ((ch & 1) ? (const unsigned int*)vT2 : (const unsigned int*)vT) +
      (ch >> 1);

  // per-lane gather walk is instance-invariant
  int tq[9], cq[9];
  {
    int ci = ci0, tap = tap0;
#pragma unroll
    for (int q = 0; q < 9; ++q) {
      tq[q] = tap;
      cq[q] = 4 + ci;
      tap += 4;
      ci += 28;
      if (tap >= 9) { tap -= 9; ci += 1; }
    }
  }

#define PV_STORE(OH, OW)                                                   \
  do {                                                                     \
    int e_ = gh_i * 6 + ((OW)-3);                                          \
    const unsigned int* vp_ = pvrow + e_ * PITCHD;                         \
    float acc_ = 0.f;                                                      \
    _Pragma("unroll") for (int j_ = 0; j_ < 5; ++j_) acc_ =                \
        dot2(vp_[j_], ap[j_], acc_);                                       \
    if ((OH) < 6 && (OW) < 6)                                              \
      acc_ = fmaf(acc_, inv_s,                                             \
                  us2f(k1T[(((OH) + 3) * 9 + ((OW) + 3)) * PITCH + 4 + ch])); \
    else                                                                   \
      acc_ *= inv_s;                                                       \
    outb[(OH)*9 + (OW)] = acc_;                                            \
  } while (0)

#pragma unroll
  for (int k = 0; k < 4; ++k) {
    if (s4 == 3 && k == 3) break;  // slot 3: 3 real instances, no dummy
    int idx = s4 * 4 + k;          // 0..14, always valid
    int gh_i = idx / 5, gw_i = idx - (idx / 5) * 5;
    int oh = (s ? 6 : 3) + gh_i;
    int gh = s ? ((gh_i + 4) % 5) : (gh_i + 1);
    int g9 = __builtin_amdgcn_readfirstlane((gh * 5 + gw_i) * 9);

    // kq gather -> packed half2 (x_q, k1_q): 2 u16 reads + 1 lshl_or per q
    unsigned int kqp[9];
#pragma unroll
    for (int q = 0; q < 9; ++q) {
      int off = (int)pixtab[g9 + tq[q]] + cq[q];
      unsigned int xv = xT[off], kv = k1T[off];
      kqp[q] = xv | (kv << 16);
    }

    __builtin_amdgcn_s_setprio(1);
    // w1 (BN-scaled pairs, fdot2, seeded with BN shift) -> ReLU
    float r[9];
#pragma unroll
    for (int o = 0; o < 9; ++o) {
      int m = g9 + o;
      const unsigned int* wp = w1p + m * 12;
      float a = bnf1[m];
#pragma unroll
      for (int q = 0; q < 9; ++q) a = dot2(kqp[q], wp[q], a);
      r[o] = fmaxf(a, 0.f);
    }

    // w2 (packed o-pairs + tail, fdot2) + b2 -> softmax (registers)
    unsigned int rp[5];
#pragma unroll
    for (int j = 0; j < 4; ++j) rp[j] = pkh2(r[2 * j], r[2 * j + 1]);
    rp[4] = pkh2(r[8], 0.f);
    float a2[9], mx = -1e30f;
#pragma unroll
    for (int d = 0; d < 9; ++d) {
      int m = g9 + d;
      const unsigned int* wq = w2p + m * 5;
      float a = b2[m];
#pragma unroll
      for (int j = 0; j < 5; ++j) a = dot2(rp[j], wq[j], a);
      a2[d] = a;
      mx = fmaxf(mx, a);
    }
    const float L2E = 1.44269504f;
    float nmL = mx * -L2E;
    float ssum = 0.f;
#pragma unroll
    for (int d = 0; d < 9; ++d) {
      a2[d] = exp2_fast(fmaf(a2[d], L2E, nmL));
      ssum += a2[d];
    }
    float inv_s = __builtin_amdgcn_rcpf(ssum);
    // pack attention weights for dot2 PV (pair 4 = (a2[8], 0))
    unsigned int ap[5];
#pragma unroll
    for (int j = 0; j < 4; ++j) ap[j] = pkh2(a2[2 * j], a2[2 * j + 1]);
    ap[4] = pkh2(a2[8], 0.f);
    __builtin_amdgcn_s_setprio(0);

    // PV + k1-add + store; gw==1 serves both ow=3 and ow=8
    int ow0 = (gw_i == 0) ? 7 : (gw_i + 2);
    PV_STORE(oh, ow0);
    if (gw_i == 1) PV_STORE(oh, 8);
  }
#undef PV_STORE

  // ---- epilogue: non-PV output pixels (all on slot 3)
  if (s4 == 3) {
    if (s == 0) {
      // rows 3..5, cols 0..2: k1-only
#pragma unroll
      for (int r0 = 0; r0 < 3; ++r0) {
        int oh = 3 + r0;
#pragma unroll
        for (int ow = 0; ow < 3; ++ow)
          outb[oh * 9 + ow] =
              us2f(k1T[((oh + 3) * 9 + (ow + 3)) * PITCH + 4 + ch]);
      }
    } else {
      // rows 0..2: k1 where ow<6, else 0
#pragma unroll
      for (int r0 = 0; r0 < 3; ++r0) {
        int oh = r0;
#pragma unroll
        for (int ow = 0; ow < 9; ++ow) {
          float v2 = 0.f;
          if (ow < 6)
            v2 = us2f(k1T[((oh + 3) * 9 + (ow + 3)) * PITCH + 4 + ch]);
          outb[oh * 9 + ow] = v2;
        }
      }
      // rows 6..8, cols 0..2: zero
#pragma unroll
      for (int r0 = 0; r0 < 3; ++r0) {
        int oh = 6 + r0;
        outb[oh * 9 + 0] = 0.f;
        outb[oh * 9 + 1] = 0.f;
        outb[oh * 9 + 2] = 0.f;
      }
    }
  }
}

extern "C" void kernel_launch(void* const* d_in, const int* in_sizes, int n_in,
                              void* d_out, int out_size, void* d_ws, size_t ws_size,
                              hipStream_t stream) {
  const float* x     = (const float*)d_in[0];
  const float* wk    = (const float*)d_in[1];
  const float* bk    = (const float*)d_in[2];
  const float* w1    = (const float*)d_in[3];
  const float* gamma = (const float*)d_in[4];
  const float* beta  = (const float*)d_in[5];
  const float* mean  = (const float*)d_in[6];
  const float* var   = (const float*)d_in[7];
  const float* w2    = (const float*)d_in[8];
  const float* b2    = (const float*)d_in[9];
  const float* wv    = (const float*)d_in[10];
  const float* bv    = (const float*)d_in[11];
  float* out = (float*)d_out;

  hipLaunchKernelGGL(semca_fused, dim3(256), dim3(1024), 0, stream,
                     x, wk, bk, w1, gamma, beta, mean, var, w2, b2, wv, bv, out);
}

// Round 19
// 24.235 us; speedup vs baseline: 1.0678x; 1.0678x over previous
//
#include <hip/hip_runtime.h>

#define C 256
#define HW 81
#define PITCH 292   // ushorts per pixel row: [4 pad][256 ch][32 pad] (even dword pitch)
#define PITCHD 146  // dwords per pixel row; 146%32=18 -> gather tap bases ~4-apart
#define ZROW 81     // zeroed row index for invalid gather taps

typedef __fp16 h2 __attribute__((ext_vector_type(2)));  // matches builtin V2h

__device__ __forceinline__ float us2f(unsigned short u) {  // f16 bits -> f32
  union { unsigned short s; __fp16 h; } c; c.s = u; return (float)c.h;
}
__device__ __forceinline__ unsigned int pkh2(float a, float b) {  // 1x cvt_pkrtz
  union { h2 h; unsigned int i; } c;
  c.h = __builtin_amdgcn_cvt_pkrtz(a, b);
  return c.i;
}
__device__ __forceinline__ h2 as_h2(unsigned int d) {
  union { unsigned int i; h2 h; } c; c.i = d; return c.h;
}
__device__ __forceinline__ unsigned int as_u32(h2 h) {
  union { h2 h; unsigned int i; } c; c.h = h; return c.i;
}
__device__ __forceinline__ float dot2(unsigned int a, unsigned int b, float c) {
#if __has_builtin(__builtin_amdgcn_fdot2)
  return __builtin_amdgcn_fdot2(as_h2(a), as_h2(b), c, false);
#else
  h2 x = as_h2(a), y = as_h2(b);
  return fmaf((float)x.y, (float)y.y, fmaf((float)x.x, (float)y.x, c));
#endif
}
__device__ __forceinline__ float exp2_fast(float x) {
#if __has_builtin(__builtin_amdgcn_exp2f)
  return __builtin_amdgcn_exp2f(x);
#else
  return __expf(x * 0.6931471805599453f);
#endif
}

// ---------------------------------------------------------------------------
// Fully fused SeMCA. Block = (b, s): s=0 -> output rows 3..5 (+epilogue rows
// 3..5 cols 0..2), s=1 -> rows 6..8 AND rows 0..2 (+zeros 6..8 cols 0..2).
// 1024 threads = 4 instance-slots x 256 channels. 2 barriers.
// R19 = exact revert to R16 (best verified, 24.39us). R17/R18's vT2 PV-dot2
// bundle regressed +1.5us (layout duplication costs > PV savings) — only
// pure instruction deletions win at this point. Diet ledger: R9 -1.63,
// R10 -0.40, R14 -0.31, R15 -0.61, R16 -0.27; structural attempts (R11,
// R17/18) both regressed. Remaining time is the 1-block/CU latency floor
// (96 KiB x/k1 gather tables forbid 2 blocks/CU; 4 waves/SIMD cap).
// ---------------------------------------------------------------------------
__global__ __launch_bounds__(1024) void semca_fused(
    const float* __restrict__ x, const float* __restrict__ wk,
    const float* __restrict__ bk, const float* __restrict__ w1,
    const float* __restrict__ gamma, const float* __restrict__ beta,
    const float* __restrict__ mean, const float* __restrict__ var,
    const float* __restrict__ w2, const float* __restrict__ b2,
    const float* __restrict__ wv, const float* __restrict__ bv,
    float* __restrict__ out) {
  __shared__ unsigned short xT[82 * PITCH];   // 47,888 B (row 81 = zeros), f16
  __shared__ unsigned short k1T[82 * PITCH];  // 47,888 B (row 81 = zeros), f16
  __shared__ unsigned short vT[18 * PITCH];   // 10,512 B, f16
  __shared__ unsigned short pixtab[228];      //    456 B (premultiplied by PITCH)
  __shared__ float bnf1[225];                 //    900 B (BN shift only)
  __shared__ unsigned int w1p[225 * 12];      // 10,800 B half2 pairs, BN-scaled
  __shared__ unsigned int w2p[225 * 4];       //  3,600 B half2 o-pairs (16B/row)
  __shared__ uint2 wkp[81 * 3];               //  1,944 B wk half2: 6 dwords/pixel

  const int blk = blockIdx.x;
  const int b = (blk & 7) * 16 + ((blk >> 3) & 15);  // XCD-paired, bijective
  const int s = blk >> 7;
  const int tid = threadIdx.x;
  const float* xb = x + (size_t)b * (C * HW);

  unsigned int* xTd = (unsigned int*)xT;
  unsigned int* k1Td = (unsigned int*)k1T;
  unsigned int* vTd = (unsigned int*)vT;
  unsigned int* wkpd = (unsigned int*)wkp;

  // ---- phase 0a: issue ALL x loads first (registers), incremental walk
  float xe[11], xo[11];
  int adr[11];
  {
    int chp = tid / HW;            // single division
    int p = tid - chp * HW;
#pragma unroll
    for (int rep = 0; rep < 10; ++rep) {
      const float* base = xb + (2 * chp) * HW + p;
      xe[rep] = base[0];
      xo[rep] = base[HW];
      adr[rep] = PITCHD * p + 2 + chp;
      chp += 12;                   // advance f by 1024 = 12*81 + 52
      p += 52;
      if (p >= HW) { p -= HW; chp += 1; }
    }
    if (tid < 128) {               // tail item f = 10240 + tid
      int f = 10240 + tid;
      int c2 = f / HW, p2 = f - c2 * HW;
      xe[10] = xb[2 * c2 * HW + p2];
      xo[10] = xb[(2 * c2 + 1) * HW + p2];
      adr[10] = PITCHD * p2 + 2 + c2;
    }
  }

  // ---- phase 0b: independent work under the load shadow
  for (int t = tid; t < 810; t += 1024) {  // x channel-pad zeros
    int p = t / 10, k2 = t - (t / 10) * 10;
    xT[p * PITCH + ((k2 < 4) ? k2 : (256 + k2))] = 0;
  }
  if (tid < PITCHD) {                      // zero row 81 of xT and k1T
    xTd[PITCHD * ZROW + tid] = 0;
    k1Td[PITCHD * ZROW + tid] = 0;
  }
  for (int t = tid; t < 225; t += 1024) {  // pixtab (premul) + BN shift
    int g = t / 9, tap = t - (t / 9) * 9;
    int kh = tap / 3, kw = tap - kh * 3;
    int h = kh * 5 + g / 5, w = kw * 5 + (g - (g / 5) * 5);
    pixtab[t] = (h < 9 && w < 9) ? (unsigned short)((h * 9 + w) * PITCH)
                                 : (unsigned short)(ZROW * PITCH);
    float inv = gamma[t] * rsqrtf(var[t] + 1e-5f);
    bnf1[t] = beta[t] - mean[t] * inv;
  }
  for (int t = tid; t < 2025; t += 1024) {  // w1 packed pairs, BN-scaled
    int m = t / 9, q = t - m * 9;
    float inv = gamma[m] * rsqrtf(var[m] + 1e-5f);
    w1p[m * 12 + q] = pkh2(w1[m * 18 + q] * inv, w1[m * 18 + 9 + q] * inv);
  }
  if (tid < 900) {                          // w2 packed o-pairs (o=0..7)
    int m = tid >> 2, j = tid & 3;
    w2p[m * 4 + j] = pkh2(w2[m * 9 + 2 * j], w2[m * 9 + 2 * j + 1]);
  }
  if (tid < 486) {                          // wk packed pairs + tails
    int m = tid / 6, j = tid - (tid / 6) * 6;
    const float* wr = wk + m * 9;
    unsigned int v;
    if (j < 4)       v = pkh2(wr[2 * j], wr[2 * j + 1]);
    else if (j == 4) v = pkh2(wr[8], 0.f);
    else             v = pkh2(0.f, wr[8]);
    wkpd[m * 6 + j] = v;
  }

  // hoisted phase-1b weights: chv fixed per thread -> packed h2 registers
  const int chv = tid & 127;
  unsigned int wvp[9];
#pragma unroll
  for (int t = 0; t < 9; ++t)
    wvp[t] = pkh2(wv[(2 * chv) * 9 + t], wv[(2 * chv + 1) * 9 + t]);
  const unsigned int bvp = pkh2(bv[2 * chv], bv[2 * chv + 1]);

  // ---- phase 0c: pack (f16) + LDS write (single drain of the x loads)
#pragma unroll
  for (int rep = 0; rep < 10; ++rep) xTd[adr[rep]] = pkh2(xe[rep], xo[rep]);
  if (tid < 128) xTd[adr[10]] = pkh2(xe[10], xo[10]);

  __syncthreads();

  // ---- phase 1a: k1[p][ch] = sum_j x[p][ch+j-4]*wk[p][j] + bk[p]
  // width-8 + symmetric row-cut: 54 rows x 32 octets = 1728 calls per half.
  {
    auto k1fn8 = [&](int p, int oct) {
      const uint2* wrow2 = (const uint2*)(xTd + PITCHD * p + 4 * oct);
      uint2 r0 = wrow2[0], r1 = wrow2[1], r2 = wrow2[2], r3 = wrow2[3];
      unsigned int W[8] = {r0.x, r0.y, r1.x, r1.y, r2.x, r2.y, r3.x, r3.y};
      unsigned int A[7];
#pragma unroll
      for (int k2 = 0; k2 < 7; ++k2)
        A[k2] = (W[k2] >> 16) | (W[k2 + 1] << 16);
      const uint2* wkq = wkp + p * 3;
      uint2 wa = wkq[0], wb = wkq[1], wc = wkq[2];
      // wa.x=(w0,w1) wa.y=(w2,w3) wb.x=(w4,w5) wb.y=(w6,w7)
      // wc.x=(w8,0)  wc.y=(0,w8)
      float bkp = bk[p];
      float cc[8];
#pragma unroll
      for (int j2 = 0; j2 < 4; ++j2) {  // even ch j=2*j2, odd ch j=2*j2+1
        cc[2 * j2] =
            dot2(W[j2], wa.x, dot2(W[j2 + 1], wa.y, dot2(W[j2 + 2], wb.x,
            dot2(W[j2 + 3], wb.y, dot2(W[j2 + 4], wc.x, bkp)))));
        cc[2 * j2 + 1] =
            dot2(A[j2], wa.x, dot2(A[j2 + 1], wa.y, dot2(A[j2 + 2], wb.x,
            dot2(A[j2 + 3], wb.y, dot2(W[j2 + 4], wc.y, bkp)))));
      }
      unsigned int* dst = k1Td + PITCHD * p + 2 + 4 * oct;
      *(uint2*)dst = make_uint2(pkh2(cc[0], cc[1]), pkh2(cc[2], cc[3]));
      *(uint2*)(dst + 2) = make_uint2(pkh2(cc[4], cc[5]), pkh2(cc[6], cc[7]));
    };
    // s=0 rows {1,2,3,6,7,8}; s=1 rows {0,1,3,4,5,6} (uniform branch)
    auto prow = [&](int f) {
      int idx = f >> 5;
      int ri = idx / 9, col = idx - ri * 9;
      int row = s == 0 ? (ri + ((ri < 3) ? 1 : 3)) : (ri + ((ri >= 2) ? 1 : 0));
      return row * 9 + col;
    };
    k1fn8(prow(tid), tid & 31);
    if (tid < 704) {
      int f = 1024 + tid;
      k1fn8(prow(f), f & 31);
    }
  }

  // ---- phase 1b: v (3x3 depthwise), packed-f16 math (pk_fma), 18 pixels
  {
    auto vfn = [&](int f) {
      int e = __builtin_amdgcn_readfirstlane(f >> 7);  // 0..17 uniform
      int r0 = e / 6;
      int i = s * 3 + r0;  // v-pixel row 0..5
      int j = e - r0 * 6;  // v-pixel col 0..5
      h2 acc = as_h2(bvp);
#pragma unroll
      for (int di = 0; di < 3; ++di) {
        int ii = i + di - 1;
        if (ii < 0) continue;  // ii <= 6 < 9 always
#pragma unroll
        for (int dj = 0; dj < 3; ++dj) {
          int jj = j + dj - 1;
          if (jj < 0) continue;  // jj <= 6 < 9 always
          unsigned int d = xTd[PITCHD * (ii * 9 + jj) + 2 + chv];
          int t = di * 3 + dj;
          acc = as_h2(d) * as_h2(wvp[t]) + acc;  // v_pk_fma_f16
        }
      }
      vTd[PITCHD * e + 2 + chv] = as_u32(acc);
    };
#pragma unroll
    for (int rep = 0; rep < 2; ++rep) vfn(tid + rep * 1024);
    if (tid < 256) vfn(2048 + tid);
  }
  if (tid < 180) {  // vT channel-pad zeros
    int e = tid / 10, k2 = tid - (tid / 10) * 10;
    vT[e * PITCH + ((k2 < 4) ? k2 : (256 + k2))] = 0;
  }
  __syncthreads();

  // ---- phase 2: 15 instances as 4/4/4/3 (slot 3 skips k=3; no dummy)
  const int s4 = tid >> 8;  // slot 0..3 (wave-uniform)
  const int ch = tid & 255;
  const int ci0 = ch / 9;
  const int tap0 = ch - ci0 * 9;
  float* outb = out + ((size_t)b * C + ch) * HW;

  // per-lane gather walk is instance-invariant
  int tq[9], cq[9];
  {
    int ci = ci0, tap = tap0;
#pragma unroll
    for (int q = 0; q < 9; ++q) {
      tq[q] = tap;
      cq[q] = 4 + ci;
      tap += 4;
      ci += 28;
      if (tap >= 9) { tap -= 9; ci += 1; }
    }
  }

#define PV_STORE(OH, OW)                                                   \
  do {                                                                     \
    int e_ = gh_i * 6 + ((OW)-3);                                          \
    const unsigned short* vrow_ = vT + e_ * PITCH;                         \
    float acc_ = 0.f;                                                      \
    _Pragma("unroll") for (int d_ = 0; d_ < 9; ++d_) acc_ =                \
        fmaf(a2[d_], us2f(vrow_[ch + d_]), acc_);                          \
    if ((OH) < 6 && (OW) < 6)                                              \
      acc_ = fmaf(acc_, inv_s,                                             \
                  us2f(k1T[(((OH) + 3) * 9 + ((OW) + 3)) * PITCH + 4 + ch])); \
    else                                                                   \
      acc_ *= inv_s;                                                       \
    outb[(OH)*9 + (OW)] = acc_;                                            \
  } while (0)

#pragma unroll
  for (int k = 0; k < 4; ++k) {
    if (s4 == 3 && k == 3) break;  // slot 3: 3 real instances, no dummy
    int idx = s4 * 4 + k;          // 0..14, always valid
    int gh_i = idx / 5, gw_i = idx - (idx / 5) * 5;
    int oh = (s ? 6 : 3) + gh_i;
    int gh = s ? ((gh_i + 4) % 5) : (gh_i + 1);
    int g9 = __builtin_amdgcn_readfirstlane((gh * 5 + gw_i) * 9);

    // kq gather -> packed half2 (x_q, k1_q): 2 u16 reads + 1 lshl_or per q
    unsigned int kqp[9];
#pragma unroll
    for (int q = 0; q < 9; ++q) {
      int off = (int)pixtab[g9 + tq[q]] + cq[q];
      unsigned int xv = xT[off], kv = k1T[off];
      kqp[q] = xv | (kv << 16);
    }

    __builtin_amdgcn_s_setprio(1);
    // w1 (BN-scaled pairs, fdot2, seeded with BN shift) -> ReLU
    float r[9];
#pragma unroll
    for (int o = 0; o < 9; ++o) {
      int m = g9 + o;
      const unsigned int* wp = w1p + m * 12;
      float a = bnf1[m];
#pragma unroll
      for (int q = 0; q < 9; ++q) a = dot2(kqp[q], wp[q], a);
      r[o] = fmaxf(a, 0.f);
    }

    // w2 (packed o-pairs, fdot2) + b2 -> softmax (registers)
    unsigned int rp[4];
#pragma unroll
    for (int j = 0; j < 4; ++j) rp[j] = pkh2(r[2 * j], r[2 * j + 1]);
    float a2[9], mx = -1e30f;
#pragma unroll
    for (int d = 0; d < 9; ++d) {
      int m = g9 + d;
      const unsigned int* wq = w2p + m * 4;
      float a = b2[m];
#pragma unroll
      for (int j = 0; j < 4; ++j) a = dot2(rp[j], wq[j], a);
      a = fmaf(w2[m * 9 + 8], r[8], a);
      a2[d] = a;
      mx = fmaxf(mx, a);
    }
    const float L2E = 1.44269504f;
    float nmL = mx * -L2E;
    float ssum = 0.f;
#pragma unroll
    for (int d = 0; d < 9; ++d) {
      a2[d] = exp2_fast(fmaf(a2[d], L2E, nmL));
      ssum += a2[d];
    }
    float inv_s = __builtin_amdgcn_rcpf(ssum);
    __builtin_amdgcn_s_setprio(0);

    // PV + k1-add + store; gw==1 serves both ow=3 and ow=8
    int ow0 = (gw_i == 0) ? 7 : (gw_i + 2);
    PV_STORE(oh, ow0);
    if (gw_i == 1) PV_STORE(oh, 8);
  }
#undef PV_STORE

  // ---- epilogue: non-PV output pixels (rebalanced: rows 0..2 on s=1)
  if (s == 0) {
    if (s4 == 3) {
      // rows 3..5, cols 0..2: k1-only
#pragma unroll
      for (int r0 = 0; r0 < 3; ++r0) {
        int oh = 3 + r0;
#pragma unroll
        for (int ow = 0; ow < 3; ++ow)
          outb[oh * 9 + ow] =
              us2f(k1T[((oh + 3) * 9 + (ow + 3)) * PITCH + 4 + ch]);
      }
    }
  } else {
    if (s4 < 3) {
      int oh = s4;  // rows 0..2: k1 where ow<6, else 0
#pragma unroll
      for (int ow = 0; ow < 9; ++ow) {
        float v2 = 0.f;
        if (ow < 6)
          v2 = us2f(k1T[((oh + 3) * 9 + (ow + 3)) * PITCH + 4 + ch]);
        outb[oh * 9 + ow] = v2;
      }
    } else {
      // rows 6..8, cols 0..2: zero
#pragma unroll
      for (int r0 = 0; r0 < 3; ++r0) {
        int oh = 6 + r0;
        outb[oh * 9 + 0] = 0.f;
        outb[oh * 9 + 1] = 0.f;
        outb[oh * 9 + 2] = 0.f;
      }
    }
  }
}

extern "C" void kernel_launch(void* const* d_in, const int* in_sizes, int n_in,
                              void* d_out, int out_size, void* d_ws, size_t ws_size,
                              hipStream_t stream) {
  const float* x     = (const float*)d_in[0];
  const float* wk    = (const float*)d_in[1];
  const float* bk    = (const float*)d_in[2];
  const float* w1    = (const float*)d_in[3];
  const float* gamma = (const float*)d_in[4];
  const float* beta  = (const float*)d_in[5];
  const float* mean  = (const float*)d_in[6];
  const float* var   = (const float*)d_in[7];
  const float* w2    = (const float*)d_in[8];
  const float* b2    = (const float*)d_in[9];
  const float* wv    = (const float*)d_in[10];
  const float* bv    = (const float*)d_in[11];
  float* out = (float*)d_out;

  hipLaunchKernelGGL(semca_fused, dim3(256), dim3(1024), 0, stream,
                     x, wk, bk, w1, gamma, beta, mean, var, w2, b2, wv, bv, out);
}